// Round 13
// baseline (139.851 us; speedup 1.0000x reference)
//
#include <hip/hip_runtime.h>
#include <math.h>

typedef short bf16x8 __attribute__((ext_vector_type(8)));
typedef float f32x4 __attribute__((ext_vector_type(4)));

#define BB 4
#define NN 256
#define HH 128
#define ME_ (BB*NN*NN)        // 262144 edge rows

// workspace float offsets (per-bi stat layout)
#define VX_OFF   0            // [1024][128] fp32 Vx
#define UX_OFF   131072       // [1024][128] fp32 Ux
#define VXN_OFF  262144       // [1024][128] u32: bf16(Vx) | bf16(Vnx)<<16
#define NUM_OFF  393216       // [1024][128] per-bi num
#define DEN_OFF  524288       // [1024][128] per-bi den (no eps)
#define PSUM_OFF 655360       // [1024][128] BN-e partial
#define PSQ_OFF  786432       // [1024][128]
#define XF_OFF   917504       // [1024][128] x_feat staging
#define PSR_OFF  1048576      // [64][128]
#define PSQR_OFF 1056768      // [64][128]
#define PSX_OFF  1064960      // [64][128]
#define PSXX_OFF 1073152      // [64][128]
#define SCE_OFF  1081344      // [128]
#define SHE_OFF  1081472      // [128]
#define SCX_OFF  1081600      // [128]
#define SHX_OFF  1081728      // [128]
#define W16_OFF  1081856      // 16384 ushort (32 KB) bf16 Ue_w

__device__ inline short f2bf(float f) {
    unsigned u = __builtin_bit_cast(unsigned, f);
    u += 0x7FFFu + ((u >> 16) & 1u);      // round-to-nearest-even
    return (short)(u >> 16);
}
__device__ inline float bfbits2f(unsigned hi) {   // bf16 bits in [31:16]
    return __builtin_bit_cast(float, hi);
}

// ---------------------------------------------------------------------------
// Kernel P: Ue_w fp32 -> bf16
// ---------------------------------------------------------------------------
__global__ __launch_bounds__(256) void k_prep(const float* __restrict__ W,
                                              unsigned short* __restrict__ W16)
{
    int i = blockIdx.x * 256 + threadIdx.x;      // grid 64
    W16[i] = (unsigned short)f2bf(W[i]);
}

// ---------------------------------------------------------------------------
// Kernel A: Vx/Vnx/Ux linears; emit Vx fp32, Ux fp32, packed bf16 (Vx,Vnx)
// ---------------------------------------------------------------------------
__global__ __launch_bounds__(256) void k_linx(
    const float* __restrict__ x,
    const float* __restrict__ Ve_w, const float* __restrict__ Ve_b,
    const float* __restrict__ Vn_w, const float* __restrict__ Vn_b,
    const float* __restrict__ Un_w, const float* __restrict__ Un_b,
    float* ws)
{
    __shared__ float xs[8 * 128];
    int t = threadIdx.x;
    int rowbase = blockIdx.x * 8;

    const float4* xg = (const float4*)(x + (size_t)rowbase * 128);
    ((float4*)xs)[t] = xg[t];
    __syncthreads();

    int h = t & 127, rh = t >> 7;
    float accV[4], accN[4], accU[4];
    float bV = Ve_b[h], bN = Vn_b[h], bU = Un_b[h];
    #pragma unroll
    for (int q = 0; q < 4; ++q) { accV[q] = bV; accN[q] = bN; accU[q] = bU; }

    const float4* wV = (const float4*)(Ve_w + (size_t)h * 128);
    const float4* wN = (const float4*)(Vn_w + (size_t)h * 128);
    const float4* wU = (const float4*)(Un_w + (size_t)h * 128);

    #pragma unroll 4
    for (int k4 = 0; k4 < 32; ++k4) {
        float4 wv = wV[k4], wn = wN[k4], wu = wU[k4];
        #pragma unroll
        for (int q = 0; q < 4; ++q) {
            float4 xv = *(const float4*)&xs[(rh + 2 * q) * 128 + k4 * 4];
            accV[q] += xv.x*wv.x + xv.y*wv.y + xv.z*wv.z + xv.w*wv.w;
            accN[q] += xv.x*wn.x + xv.y*wn.y + xv.z*wn.z + xv.w*wn.w;
            accU[q] += xv.x*wu.x + xv.y*wu.y + xv.z*wu.z + xv.w*wu.w;
        }
    }
    unsigned* VXN = (unsigned*)(ws + VXN_OFF);
    #pragma unroll
    for (int q = 0; q < 4; ++q) {
        size_t idx = (size_t)(rowbase + rh + 2 * q) * 128 + h;
        ws[VX_OFF + idx] = accV[q];
        ws[UX_OFF + idx] = accU[q];
        VXN[idx] = ((unsigned)(unsigned short)f2bf(accV[q]))
                 | ((unsigned)(unsigned short)f2bf(accN[q]) << 16);
    }
}

// ---------------------------------------------------------------------------
// helpers for the edge passes
// ---------------------------------------------------------------------------
__device__ inline void load_raw(const float* __restrict__ eb, int row, int g,
                                float4* raw)
{
    const float* rp = eb + (size_t)row * 128 + g * 8;
    #pragma unroll
    for (int kc = 0; kc < 4; ++kc) {
        raw[2*kc]   = *(const float4*)(rp + kc * 32);
        raw[2*kc+1] = *(const float4*)(rp + kc * 32 + 4);
    }
}
__device__ inline void cvt_frag(const float4* raw, bf16x8* afr)
{
    #pragma unroll
    for (int kc = 0; kc < 4; ++kc) {
        float4 f0 = raw[2*kc], f1 = raw[2*kc+1];
        bf16x8 a;
        a[0] = f2bf(f0.x); a[1] = f2bf(f0.y); a[2] = f2bf(f0.z); a[3] = f2bf(f0.w);
        a[4] = f2bf(f1.x); a[5] = f2bf(f1.y); a[6] = f2bf(f1.z); a[7] = f2bf(f1.w);
        afr[kc] = a;
    }
}
__device__ inline bf16x8 ldsW(const short* Wl, int h, int kc, int g, int swz)
{
    return *(const bf16x8*)((const char*)Wl + h * 256 + ((kc * 64 + g * 16) ^ swz));
}

// ---------------------------------------------------------------------------
// Pass 1 (stats): grid 1024 = bi. One block covers all 256 j via an OUTER
// NON-UNROLLED loop over 2 j-halves (W staged ONCE per bi — halves staging
// overhead vs grid-2048 — while register liveness stays at R9's 2-tile
// level; R11's regression was the 4-tile full unroll, not amortization).
// Inner body identical to R9's pressure-minimal form. num/den/BN-e
// accumulate across both halves -> per-bi partials.
// ---------------------------------------------------------------------------
__global__ __launch_bounds__(256) void k_edge_stats(
    const float* __restrict__ e,
    const unsigned short* __restrict__ W16,
    const float* __restrict__ Ue_b,
    float* __restrict__ ws)
{
    __shared__ short Wl[16384];     // 32 KB bf16 W, XOR-swizzled
    __shared__ float red[2048];     // [4 stats][4 waves][128]
    int t   = threadIdx.x;
    int bi  = blockIdx.x;           // 0..1023
    int b   = bi >> 8;
    int wid = t >> 6, l = t & 63;
    int hsub = l & 15, g = l >> 4;
    int swz = (hsub & 7) << 4;

    const unsigned* VXNb = (const unsigned*)(ws + VXN_OFF) + (size_t)b * 32768;
    const float* eb = e + (size_t)bi * 32768;

    // pre-barrier: item-0 tile-0 raw + bias in flight, cover W-staging latency
    float4 raw[8];
    load_raw(eb, wid * 32 + hsub, g, raw);

    float biasv[8];
    #pragma unroll
    for (int ct = 0; ct < 8; ++ct) {
        int h = ct * 16 + hsub;
        biasv[ct] = Ue_b[h] + ws[VX_OFF + (size_t)bi * 128 + h];
    }

    const int4* Wg = (const int4*)W16;
    #pragma unroll
    for (int p = 0; p < 8; ++p) {
        int s = t + 256 * p;
        int r = s >> 4, c = s & 15;
        int addr = r * 256 + ((c * 16) ^ ((r & 7) << 4));
        *(int4*)((char*)Wl + addr) = Wg[s];
    }
    __syncthreads();

    float num[8] = {0,0,0,0,0,0,0,0}, den[8] = {0,0,0,0,0,0,0,0};
    float se[8]  = {0,0,0,0,0,0,0,0}, sq[8]  = {0,0,0,0,0,0,0,0};

    bf16x8 afr[4];

    #pragma unroll 1
    for (int jh = 0; jh < 2; ++jh) {
        int jbase = jh * 128 + wid * 32;

        #pragma unroll
        for (int rt = 0; rt < 2; ++rt) {
            int jb = jbase + rt * 16;
            cvt_frag(raw, afr);
            if (rt == 0)
                load_raw(eb, jbase + 16 + hsub, g, raw);          // tile 1
            else if (jh == 0)
                load_raw(eb, 128 + wid * 32 + hsub, g, raw);      // next item tile 0

            #pragma unroll
            for (int ct = 0; ct < 8; ++ct) {
                int h = ct * 16 + hsub;

                unsigned pk[4];
                #pragma unroll
                for (int r = 0; r < 4; ++r)
                    pk[r] = VXNb[(size_t)(jb + g * 4 + r) * 128 + h];

                f32x4 acc = {0.f, 0.f, 0.f, 0.f};
                #pragma unroll
                for (int kc = 0; kc < 4; ++kc)
                    acc = __builtin_amdgcn_mfma_f32_16x16x32_bf16(
                              afr[kc], ldsW(Wl, h, kc, g, swz), acc, 0, 0, 0);

                float bih = biasv[ct];
                #pragma unroll
                for (int r = 0; r < 4; ++r) {
                    float vx  = bfbits2f(pk[r] << 16);
                    float vnx = bfbits2f(pk[r] & 0xFFFF0000u);
                    float v = acc[r] + bih + vx;
                    float gv = __builtin_amdgcn_rcpf(1.0f + __expf(-v));
                    num[ct] += gv * vnx;
                    den[ct] += gv;
                    se[ct]  += v;
                    sq[ct]  += v * v;
                }
            }
        }
    }

    #pragma unroll
    for (int ct = 0; ct < 8; ++ct) {
        float n = num[ct], d = den[ct], s1 = se[ct], s2 = sq[ct];
        n  += __shfl_xor(n, 32);  n  += __shfl_xor(n, 16);
        d  += __shfl_xor(d, 32);  d  += __shfl_xor(d, 16);
        s1 += __shfl_xor(s1, 32); s1 += __shfl_xor(s1, 16);
        s2 += __shfl_xor(s2, 32); s2 += __shfl_xor(s2, 16);
        if (l < 16) {
            int h = ct * 16 + l;
            red[0 * 512 + wid * 128 + h] = n;
            red[1 * 512 + wid * 128 + h] = d;
            red[2 * 512 + wid * 128 + h] = s1;
            red[3 * 512 + wid * 128 + h] = s2;
        }
    }
    __syncthreads();
    if (t < 128) {
        int h = t;
        float sn = 0.f, sd = 0.f;
        #pragma unroll
        for (int w = 0; w < 4; ++w) {
            sn += red[0 * 512 + w * 128 + h];
            sd += red[1 * 512 + w * 128 + h];
        }
        ws[NUM_OFF + (size_t)bi * 128 + h] = sn;
        ws[DEN_OFF + (size_t)bi * 128 + h] = sd;
    } else {
        int h = t - 128;
        float s1 = 0.f, s2 = 0.f;
        #pragma unroll
        for (int w = 0; w < 4; ++w) {
            s1 += red[2 * 512 + w * 128 + h];
            s2 += red[3 * 512 + w * 128 + h];
        }
        ws[PSUM_OFF + (size_t)bi * 128 + h] = s1;
        ws[PSQ_OFF  + (size_t)bi * 128 + h] = s2;
    }
}

// ---------------------------------------------------------------------------
// k_red (grid 64): coalesced partial reductions + x_feat staging (per-bi).
// ---------------------------------------------------------------------------
__global__ __launch_bounds__(256) void k_red(float* ws)
{
    __shared__ float sm[1024];      // [4 stats][2 p][128]
    int t = threadIdx.x, bid = blockIdx.x;
    int h = t & 127, p = t >> 7;

    float s1 = 0.f, s2 = 0.f, sx = 0.f, sxx = 0.f;
    #pragma unroll
    for (int q = 0; q < 8; ++q) {
        int bi = bid * 16 + p * 8 + q;          // 1024 bi over 64 blocks
        size_t idx = (size_t)bi * 128 + h;
        s1 += ws[PSUM_OFF + idx];
        s2 += ws[PSQ_OFF + idx];
        float nm = ws[NUM_OFF + idx];
        float dn = 1e-20f + ws[DEN_OFF + idx];
        float v = ws[UX_OFF + idx] + nm / dn;
        ws[XF_OFF + idx] = v;
        sx += v; sxx += v * v;
    }
    sm[0 * 256 + p * 128 + h] = s1;
    sm[1 * 256 + p * 128 + h] = s2;
    sm[2 * 256 + p * 128 + h] = sx;
    sm[3 * 256 + p * 128 + h] = sxx;
    __syncthreads();
    if (t < 128) {
        ws[PSR_OFF  + (size_t)bid * 128 + h] = sm[0*256 + h] + sm[0*256 + 128 + h];
        ws[PSQR_OFF + (size_t)bid * 128 + h] = sm[1*256 + h] + sm[1*256 + 128 + h];
    } else {
        ws[PSX_OFF  + (size_t)bid * 128 + h] = sm[2*256 + h] + sm[2*256 + 128 + h];
        ws[PSXX_OFF + (size_t)bid * 128 + h] = sm[3*256 + h] + sm[3*256 + 128 + h];
    }
}

// ---------------------------------------------------------------------------
// k_fin (1 block, 128 threads): per-h BN constants (e and x, folded)
// ---------------------------------------------------------------------------
__global__ __launch_bounds__(128) void k_fin(
    const float* __restrict__ bn_x_g, const float* __restrict__ bn_x_b,
    const float* __restrict__ bn_e_g, const float* __restrict__ bn_e_b,
    float* ws)
{
    int h = threadIdx.x;
    float s1 = 0.f, s2 = 0.f, sx = 0.f, sxx = 0.f;
    for (int r = 0; r < 64; ++r) {
        size_t idx = (size_t)r * 128 + h;
        s1 += ws[PSR_OFF + idx];
        s2 += ws[PSQR_OFF + idx];
        sx += ws[PSX_OFF + idx];
        sxx+= ws[PSXX_OFF + idx];
    }
    float me = s1 / (float)ME_;
    float ve = s2 / (float)ME_ - me * me;
    float sce = bn_e_g[h] * rsqrtf(ve + 1e-5f);
    ws[SCE_OFF + h] = sce;
    ws[SHE_OFF + h] = bn_e_b[h] - me * sce;
    float mx = sx / 1024.0f;
    float vx = sxx / 1024.0f - mx * mx;
    float scx = bn_x_g[h] * rsqrtf(vx + 1e-5f);
    ws[SCX_OFF + h] = scx;
    ws[SHX_OFF + h] = bn_x_b[h] - mx * scx;
}

// ---------------------------------------------------------------------------
// k_xnew (grid 128): x_new = x + relu(xf*scx + shx), float4 streaming
// ---------------------------------------------------------------------------
__global__ __launch_bounds__(256) void k_xnew(
    const float* __restrict__ x, const float* __restrict__ ws,
    float* __restrict__ out_x)
{
    __shared__ float sc[128], sh[128];
    int t = threadIdx.x;
    if (t < 128) sc[t] = ws[SCX_OFF + t];
    else         sh[t - 128] = ws[SHX_OFF + t - 128];
    __syncthreads();

    int i4 = blockIdx.x * 256 + t;               // 32768 float4
    int hb = (i4 & 31) * 4;
    float4 scv = *(const float4*)&sc[hb];
    float4 shv = *(const float4*)&sh[hb];
    float4 xf = ((const float4*)(ws + XF_OFF))[i4];
    float4 xv = ((const float4*)x)[i4];
    float4 o;
    o.x = xv.x + fmaxf(xf.x * scv.x + shv.x, 0.0f);
    o.y = xv.y + fmaxf(xf.y * scv.y + shv.y, 0.0f);
    o.z = xv.z + fmaxf(xf.z * scv.z + shv.z, 0.0f);
    o.w = xv.w + fmaxf(xf.w * scv.w + shv.w, 0.0f);
    ((float4*)out_x)[i4] = o;
}

// ---------------------------------------------------------------------------
// Pass 2 (apply): recompute e_feat (A=e, B=W; C col=h -> coalesced), write
// e_new = e + relu(e_feat * sce[h] + she[h]). R5/R9-measured version:
// scalar VXf/er gathers with 1-ct lookahead, launch_bounds (256,3).
// ---------------------------------------------------------------------------
__global__ __launch_bounds__(256, 3) void k_edge_apply(
    const float* __restrict__ e,
    const unsigned short* __restrict__ W16,
    const float* __restrict__ Ue_b,
    const float* __restrict__ ws,
    float* __restrict__ out_e)
{
    __shared__ short Wl[16384];     // 32 KB bf16 W, swizzled
    int t   = threadIdx.x;
    int bx  = blockIdx.x;
    int bi  = bx >> 1, jh = bx & 1;
    int b   = bi >> 8;
    int wid = t >> 6, l = t & 63;
    int hsub = l & 15, g = l >> 4;
    int swz = (hsub & 7) << 4;
    int jbase = jh * 128 + wid * 32;

    const float* VXf  = ws + VX_OFF + (size_t)b * 32768;
    const float* eb   = e     + (size_t)bi * 32768;
    float*       oute = out_e + (size_t)bi * 32768;

    // pre-barrier issue: tile-0 raws + ct-0 operands + constants
    float4 raw[8];
    load_raw(eb, jbase + hsub, g, raw);
    float vx_pre[4], er_pre[4];
    #pragma unroll
    for (int r = 0; r < 4; ++r) {
        size_t idx = (size_t)(jbase + g * 4 + r) * 128 + hsub;
        vx_pre[r] = VXf[idx];
        er_pre[r] = eb[idx];
    }
    float biasv[8], sceR[8], sheR[8];
    #pragma unroll
    for (int ct = 0; ct < 8; ++ct) {
        int h = ct * 16 + hsub;
        biasv[ct] = Ue_b[h] + ws[VX_OFF + (size_t)bi * 128 + h];
        sceR[ct]  = ws[SCE_OFF + h];
        sheR[ct]  = ws[SHE_OFF + h];
    }

    const int4* Wg = (const int4*)W16;
    #pragma unroll
    for (int p = 0; p < 8; ++p) {
        int s = t + 256 * p;
        int r = s >> 4, c = s & 15;
        int addr = r * 256 + ((c * 16) ^ ((r & 7) << 4));
        *(int4*)((char*)Wl + addr) = Wg[s];
    }
    __syncthreads();

    bf16x8 afr[4];

    #pragma unroll
    for (int rt = 0; rt < 2; ++rt) {
        int jb = jbase + rt * 16;
        cvt_frag(raw, afr);
        if (rt == 0) load_raw(eb, jbase + 16 + hsub, g, raw);

        float vx_n[4], er_n[4];
        bf16x8 bfr_n[4];
        #pragma unroll
        for (int r = 0; r < 4; ++r) {
            if (rt == 0) { vx_n[r] = vx_pre[r]; er_n[r] = er_pre[r]; }
            else {
                size_t idx = (size_t)(jb + g * 4 + r) * 128 + hsub;
                vx_n[r] = VXf[idx];
                er_n[r] = eb[idx];
            }
        }
        #pragma unroll
        for (int kc = 0; kc < 4; ++kc) bfr_n[kc] = ldsW(Wl, hsub, kc, g, swz);

        #pragma unroll
        for (int ct = 0; ct < 8; ++ct) {
            float vx_c[4], er_c[4];
            bf16x8 bfr_c[4];
            #pragma unroll
            for (int r = 0; r < 4; ++r) { vx_c[r] = vx_n[r]; er_c[r] = er_n[r]; }
            #pragma unroll
            for (int kc = 0; kc < 4; ++kc) bfr_c[kc] = bfr_n[kc];

            if (ct < 7) {
                int hn = (ct + 1) * 16 + hsub;
                #pragma unroll
                for (int r = 0; r < 4; ++r) {
                    size_t idx = (size_t)(jb + g * 4 + r) * 128 + hn;
                    vx_n[r] = VXf[idx];
                    er_n[r] = eb[idx];
                }
                #pragma unroll
                for (int kc = 0; kc < 4; ++kc)
                    bfr_n[kc] = ldsW(Wl, hn, kc, g, swz);
            }

            f32x4 acc = {0.f, 0.f, 0.f, 0.f};
            #pragma unroll
            for (int kc = 0; kc < 4; ++kc)
                acc = __builtin_amdgcn_mfma_f32_16x16x32_bf16(afr[kc], bfr_c[kc], acc, 0, 0, 0);

            float bih = biasv[ct], sc = sceR[ct], sh = sheR[ct];
            int h = ct * 16 + hsub;
            #pragma unroll
            for (int r = 0; r < 4; ++r) {
                int j = jb + g * 4 + r;
                float v = acc[r] + bih + vx_c[r];
                float f = v * sc + sh;
                oute[(size_t)j * 128 + h] = er_c[r] + fmaxf(f, 0.0f);
            }
        }
    }
}

extern "C" void kernel_launch(void* const* d_in, const int* in_sizes, int n_in,
                              void* d_out, int out_size, void* d_ws, size_t ws_size,
                              hipStream_t stream)
{
    const float* x      = (const float*)d_in[0];
    const float* e      = (const float*)d_in[1];
    const float* Ue_w   = (const float*)d_in[2];
    const float* Ue_b   = (const float*)d_in[3];
    const float* Ve_w   = (const float*)d_in[4];
    const float* Ve_b   = (const float*)d_in[5];
    const float* Un_w   = (const float*)d_in[6];
    const float* Un_b   = (const float*)d_in[7];
    const float* Vn_w   = (const float*)d_in[8];
    const float* Vn_b   = (const float*)d_in[9];
    const float* bn_x_g = (const float*)d_in[10];
    const float* bn_x_b = (const float*)d_in[11];
    const float* bn_e_g = (const float*)d_in[12];
    const float* bn_e_b = (const float*)d_in[13];

    float* out   = (float*)d_out;
    float* out_x = out;                 // 131072 floats
    float* out_e = out + 131072;        // 33554432 floats
    float* ws    = (float*)d_ws;
    unsigned short* W16 = (unsigned short*)(ws + W16_OFF);

    k_prep       <<<64, 256, 0, stream>>>(Ue_w, W16);
    k_linx       <<<128, 256, 0, stream>>>(x, Ve_w, Ve_b, Vn_w, Vn_b, Un_w, Un_b, ws);
    k_edge_stats <<<1024, 256, 0, stream>>>(e, W16, Ue_b, ws);
    k_red        <<<64, 256, 0, stream>>>(ws);
    k_fin        <<<1, 128, 0, stream>>>(bn_x_g, bn_x_b, bn_e_g, bn_e_b, ws);
    k_xnew       <<<128, 256, 0, stream>>>(x, ws, out_x);
    k_edge_apply <<<2048, 256, 0, stream>>>(e, W16, Ue_b, ws, out_e);
}

// Round 14
// 131.786 us; speedup vs baseline: 1.0612x; 1.0612x over previous
//
#include <hip/hip_runtime.h>
#include <math.h>

typedef short bf16x8 __attribute__((ext_vector_type(8)));
typedef float f32x4 __attribute__((ext_vector_type(4)));

#define BB 4
#define NN 256
#define HH 128
#define ME_ (BB*NN*NN)        // 262144 edge rows

// workspace float offsets
#define VX_OFF   0            // [1024][128] fp32 Vx
#define UX_OFF   131072       // [1024][128] fp32 Ux
#define VXN_OFF  262144       // [1024][128] u32: bf16(Vx) | bf16(Vnx)<<16
#define NUM_OFF  393216       // [2048][128] per-half partial
#define DEN_OFF  655360       // [2048][128] per-half partial (no eps)
#define PSUM_OFF 917504       // [2048][128] BN-e partial
#define PSQ_OFF  1179648      // [2048][128]
#define XF_OFF   1441792      // [1024][128] x_feat staging
#define PSR_OFF  1572864      // [64][128]
#define PSQR_OFF 1581056      // [64][128]
#define PSX_OFF  1589248      // [64][128]
#define PSXX_OFF 1597440      // [64][128]
#define SCE_OFF  1605632      // [128]
#define SHE_OFF  1605760      // [128]
#define SCX_OFF  1605888      // [128]
#define SHX_OFF  1606016      // [128]
#define W16_OFF  1606144      // 16384 ushort (32 KB) bf16 Ue_w

__device__ inline short f2bf(float f) {
    unsigned u = __builtin_bit_cast(unsigned, f);
    u += 0x7FFFu + ((u >> 16) & 1u);      // round-to-nearest-even
    return (short)(u >> 16);
}
__device__ inline float bfbits2f(unsigned hi) {   // bf16 bits in [31:16]
    return __builtin_bit_cast(float, hi);
}

// ---------------------------------------------------------------------------
// Kernel P: Ue_w fp32 -> bf16
// ---------------------------------------------------------------------------
__global__ __launch_bounds__(256) void k_prep(const float* __restrict__ W,
                                              unsigned short* __restrict__ W16)
{
    int i = blockIdx.x * 256 + threadIdx.x;      // grid 64
    W16[i] = (unsigned short)f2bf(W[i]);
}

// ---------------------------------------------------------------------------
// Kernel A: Vx/Vnx/Ux linears; emit Vx fp32, Ux fp32, packed bf16 (Vx,Vnx)
// ---------------------------------------------------------------------------
__global__ __launch_bounds__(256) void k_linx(
    const float* __restrict__ x,
    const float* __restrict__ Ve_w, const float* __restrict__ Ve_b,
    const float* __restrict__ Vn_w, const float* __restrict__ Vn_b,
    const float* __restrict__ Un_w, const float* __restrict__ Un_b,
    float* ws)
{
    __shared__ float xs[8 * 128];
    int t = threadIdx.x;
    int rowbase = blockIdx.x * 8;

    const float4* xg = (const float4*)(x + (size_t)rowbase * 128);
    ((float4*)xs)[t] = xg[t];
    __syncthreads();

    int h = t & 127, rh = t >> 7;
    float accV[4], accN[4], accU[4];
    float bV = Ve_b[h], bN = Vn_b[h], bU = Un_b[h];
    #pragma unroll
    for (int q = 0; q < 4; ++q) { accV[q] = bV; accN[q] = bN; accU[q] = bU; }

    const float4* wV = (const float4*)(Ve_w + (size_t)h * 128);
    const float4* wN = (const float4*)(Vn_w + (size_t)h * 128);
    const float4* wU = (const float4*)(Un_w + (size_t)h * 128);

    #pragma unroll 4
    for (int k4 = 0; k4 < 32; ++k4) {
        float4 wv = wV[k4], wn = wN[k4], wu = wU[k4];
        #pragma unroll
        for (int q = 0; q < 4; ++q) {
            float4 xv = *(const float4*)&xs[(rh + 2 * q) * 128 + k4 * 4];
            accV[q] += xv.x*wv.x + xv.y*wv.y + xv.z*wv.z + xv.w*wv.w;
            accN[q] += xv.x*wn.x + xv.y*wn.y + xv.z*wn.z + xv.w*wn.w;
            accU[q] += xv.x*wu.x + xv.y*wu.y + xv.z*wu.z + xv.w*wu.w;
        }
    }
    unsigned* VXN = (unsigned*)(ws + VXN_OFF);
    #pragma unroll
    for (int q = 0; q < 4; ++q) {
        size_t idx = (size_t)(rowbase + rh + 2 * q) * 128 + h;
        ws[VX_OFF + idx] = accV[q];
        ws[UX_OFF + idx] = accU[q];
        VXN[idx] = ((unsigned)(unsigned short)f2bf(accV[q]))
                 | ((unsigned)(unsigned short)f2bf(accN[q]) << 16);
    }
}

// ---------------------------------------------------------------------------
// helpers for the edge passes
// ---------------------------------------------------------------------------
__device__ inline void load_raw(const float* __restrict__ eb, int row, int g,
                                float4* raw)
{
    const float* rp = eb + (size_t)row * 128 + g * 8;
    #pragma unroll
    for (int kc = 0; kc < 4; ++kc) {
        raw[2*kc]   = *(const float4*)(rp + kc * 32);
        raw[2*kc+1] = *(const float4*)(rp + kc * 32 + 4);
    }
}
__device__ inline void cvt_frag(const float4* raw, bf16x8* afr)
{
    #pragma unroll
    for (int kc = 0; kc < 4; ++kc) {
        float4 f0 = raw[2*kc], f1 = raw[2*kc+1];
        bf16x8 a;
        a[0] = f2bf(f0.x); a[1] = f2bf(f0.y); a[2] = f2bf(f0.z); a[3] = f2bf(f0.w);
        a[4] = f2bf(f1.x); a[5] = f2bf(f1.y); a[6] = f2bf(f1.z); a[7] = f2bf(f1.w);
        afr[kc] = a;
    }
}
__device__ inline bf16x8 ldsW(const short* Wl, int h, int kc, int g, int swz)
{
    return *(const bf16x8*)((const char*)Wl + h * 256 + ((kc * 64 + g * 16) ^ swz));
}

// ---------------------------------------------------------------------------
// Pass 1 (stats): grid 2048 = (bi, j-half). e_feat in-register via MFMA;
// sigmoid; num/den; BN-e partials. PRESSURE-MINIMAL (R9-measured best):
// plain loads, full unroll, compiler schedules, no min-waves bound.
// ---------------------------------------------------------------------------
__global__ __launch_bounds__(256) void k_edge_stats(
    const float* __restrict__ e,
    const unsigned short* __restrict__ W16,
    const float* __restrict__ Ue_b,
    float* __restrict__ ws)
{
    __shared__ short Wl[16384];     // 32 KB bf16 W, XOR-swizzled
    __shared__ float red[2048];     // [4 stats][4 waves][128]
    int t   = threadIdx.x;
    int bx  = blockIdx.x;
    int bi  = bx >> 1, jh = bx & 1;
    int b   = bi >> 8;
    int wid = t >> 6, l = t & 63;
    int hsub = l & 15, g = l >> 4;
    int swz = (hsub & 7) << 4;
    int jbase = jh * 128 + wid * 32;

    const unsigned* VXNb = (const unsigned*)(ws + VXN_OFF) + (size_t)b * 32768;
    const float* eb = e + (size_t)bi * 32768;

    // pre-barrier: tile-0 raw + bias in flight, cover W-staging latency
    float4 raw[8];
    load_raw(eb, jbase + hsub, g, raw);

    float biasv[8];
    #pragma unroll
    for (int ct = 0; ct < 8; ++ct) {
        int h = ct * 16 + hsub;
        biasv[ct] = Ue_b[h] + ws[VX_OFF + (size_t)bi * 128 + h];
    }

    const int4* Wg = (const int4*)W16;
    #pragma unroll
    for (int p = 0; p < 8; ++p) {
        int s = t + 256 * p;
        int r = s >> 4, c = s & 15;
        int addr = r * 256 + ((c * 16) ^ ((r & 7) << 4));
        *(int4*)((char*)Wl + addr) = Wg[s];
    }
    __syncthreads();

    float num[8] = {0,0,0,0,0,0,0,0}, den[8] = {0,0,0,0,0,0,0,0};
    float se[8]  = {0,0,0,0,0,0,0,0}, sq[8]  = {0,0,0,0,0,0,0,0};

    bf16x8 afr[4];

    #pragma unroll
    for (int rt = 0; rt < 2; ++rt) {
        int jb = jbase + rt * 16;
        cvt_frag(raw, afr);
        if (rt == 0) load_raw(eb, jbase + 16 + hsub, g, raw);  // tile 1 in flight

        #pragma unroll
        for (int ct = 0; ct < 8; ++ct) {
            int h = ct * 16 + hsub;

            unsigned pk[4];
            #pragma unroll
            for (int r = 0; r < 4; ++r)
                pk[r] = VXNb[(size_t)(jb + g * 4 + r) * 128 + h];

            f32x4 acc = {0.f, 0.f, 0.f, 0.f};
            #pragma unroll
            for (int kc = 0; kc < 4; ++kc)
                acc = __builtin_amdgcn_mfma_f32_16x16x32_bf16(
                          afr[kc], ldsW(Wl, h, kc, g, swz), acc, 0, 0, 0);

            float bih = biasv[ct];
            #pragma unroll
            for (int r = 0; r < 4; ++r) {
                float vx  = bfbits2f(pk[r] << 16);
                float vnx = bfbits2f(pk[r] & 0xFFFF0000u);
                float v = acc[r] + bih + vx;
                float gv = __builtin_amdgcn_rcpf(1.0f + __expf(-v));
                num[ct] += gv * vnx;
                den[ct] += gv;
                se[ct]  += v;
                sq[ct]  += v * v;
            }
        }
    }

    #pragma unroll
    for (int ct = 0; ct < 8; ++ct) {
        float n = num[ct], d = den[ct], s1 = se[ct], s2 = sq[ct];
        n  += __shfl_xor(n, 32);  n  += __shfl_xor(n, 16);
        d  += __shfl_xor(d, 32);  d  += __shfl_xor(d, 16);
        s1 += __shfl_xor(s1, 32); s1 += __shfl_xor(s1, 16);
        s2 += __shfl_xor(s2, 32); s2 += __shfl_xor(s2, 16);
        if (l < 16) {
            int h = ct * 16 + l;
            red[0 * 512 + wid * 128 + h] = n;
            red[1 * 512 + wid * 128 + h] = d;
            red[2 * 512 + wid * 128 + h] = s1;
            red[3 * 512 + wid * 128 + h] = s2;
        }
    }
    __syncthreads();
    if (t < 128) {
        int h = t;
        float sn = 0.f, sd = 0.f;
        #pragma unroll
        for (int w = 0; w < 4; ++w) {
            sn += red[0 * 512 + w * 128 + h];
            sd += red[1 * 512 + w * 128 + h];
        }
        ws[NUM_OFF + (size_t)bx * 128 + h] = sn;
        ws[DEN_OFF + (size_t)bx * 128 + h] = sd;
    } else {
        int h = t - 128;
        float s1 = 0.f, s2 = 0.f;
        #pragma unroll
        for (int w = 0; w < 4; ++w) {
            s1 += red[2 * 512 + w * 128 + h];
            s2 += red[3 * 512 + w * 128 + h];
        }
        ws[PSUM_OFF + (size_t)bx * 128 + h] = s1;
        ws[PSQ_OFF  + (size_t)bx * 128 + h] = s2;
    }
}

// ---------------------------------------------------------------------------
// k_red (grid 64): coalesced partial reductions + x_feat staging.
// ---------------------------------------------------------------------------
__global__ __launch_bounds__(256) void k_red(float* ws)
{
    __shared__ float sm[1024];      // [4 stats][2 p][128]
    int t = threadIdx.x, bid = blockIdx.x;
    int h = t & 127, p = t >> 7;

    float s1 = 0.f, s2 = 0.f;
    #pragma unroll
    for (int q = 0; q < 16; ++q) {
        size_t idx = (size_t)(bid * 32 + p * 16 + q) * 128 + h;
        s1 += ws[PSUM_OFF + idx];
        s2 += ws[PSQ_OFF + idx];
    }
    float sx = 0.f, sxx = 0.f;
    #pragma unroll
    for (int q = 0; q < 8; ++q) {
        int bi = bid * 16 + p * 8 + q;
        size_t i0 = (size_t)(2 * bi) * 128 + h, i1 = (size_t)(2 * bi + 1) * 128 + h;
        float nm = ws[NUM_OFF + i0] + ws[NUM_OFF + i1];
        float dn = 1e-20f + ws[DEN_OFF + i0] + ws[DEN_OFF + i1];
        float v = ws[UX_OFF + (size_t)bi * 128 + h] + nm / dn;
        ws[XF_OFF + (size_t)bi * 128 + h] = v;
        sx += v; sxx += v * v;
    }
    sm[0 * 256 + p * 128 + h] = s1;
    sm[1 * 256 + p * 128 + h] = s2;
    sm[2 * 256 + p * 128 + h] = sx;
    sm[3 * 256 + p * 128 + h] = sxx;
    __syncthreads();
    if (t < 128) {
        ws[PSR_OFF  + (size_t)bid * 128 + h] = sm[0*256 + h] + sm[0*256 + 128 + h];
        ws[PSQR_OFF + (size_t)bid * 128 + h] = sm[1*256 + h] + sm[1*256 + 128 + h];
    } else {
        ws[PSX_OFF  + (size_t)bid * 128 + h] = sm[2*256 + h] + sm[2*256 + 128 + h];
        ws[PSXX_OFF + (size_t)bid * 128 + h] = sm[3*256 + h] + sm[3*256 + 128 + h];
    }
}

// ---------------------------------------------------------------------------
// k_fin (1 block, 128 threads): per-h BN constants (e and x, folded)
// ---------------------------------------------------------------------------
__global__ __launch_bounds__(128) void k_fin(
    const float* __restrict__ bn_x_g, const float* __restrict__ bn_x_b,
    const float* __restrict__ bn_e_g, const float* __restrict__ bn_e_b,
    float* ws)
{
    int h = threadIdx.x;
    float s1 = 0.f, s2 = 0.f, sx = 0.f, sxx = 0.f;
    for (int r = 0; r < 64; ++r) {
        size_t idx = (size_t)r * 128 + h;
        s1 += ws[PSR_OFF + idx];
        s2 += ws[PSQR_OFF + idx];
        sx += ws[PSX_OFF + idx];
        sxx+= ws[PSXX_OFF + idx];
    }
    float me = s1 / (float)ME_;
    float ve = s2 / (float)ME_ - me * me;
    float sce = bn_e_g[h] * rsqrtf(ve + 1e-5f);
    ws[SCE_OFF + h] = sce;
    ws[SHE_OFF + h] = bn_e_b[h] - me * sce;
    float mx = sx / 1024.0f;
    float vx = sxx / 1024.0f - mx * mx;
    float scx = bn_x_g[h] * rsqrtf(vx + 1e-5f);
    ws[SCX_OFF + h] = scx;
    ws[SHX_OFF + h] = bn_x_b[h] - mx * scx;
}

// ---------------------------------------------------------------------------
// k_xnew (grid 128): x_new = x + relu(xf*scx + shx), float4 streaming
// ---------------------------------------------------------------------------
__global__ __launch_bounds__(256) void k_xnew(
    const float* __restrict__ x, const float* __restrict__ ws,
    float* __restrict__ out_x)
{
    __shared__ float sc[128], sh[128];
    int t = threadIdx.x;
    if (t < 128) sc[t] = ws[SCX_OFF + t];
    else         sh[t - 128] = ws[SHX_OFF + t - 128];
    __syncthreads();

    int i4 = blockIdx.x * 256 + t;               // 32768 float4
    int hb = (i4 & 31) * 4;
    float4 scv = *(const float4*)&sc[hb];
    float4 shv = *(const float4*)&sh[hb];
    float4 xf = ((const float4*)(ws + XF_OFF))[i4];
    float4 xv = ((const float4*)x)[i4];
    float4 o;
    o.x = xv.x + fmaxf(xf.x * scv.x + shv.x, 0.0f);
    o.y = xv.y + fmaxf(xf.y * scv.y + shv.y, 0.0f);
    o.z = xv.z + fmaxf(xf.z * scv.z + shv.z, 0.0f);
    o.w = xv.w + fmaxf(xf.w * scv.w + shv.w, 0.0f);
    ((float4*)out_x)[i4] = o;
}

// ---------------------------------------------------------------------------
// Pass 2 (apply): recompute e_feat (A=e, B=W; C col=h -> coalesced), write
// e_new = e + relu(e_feat * sce[h] + she[h]). R5/R9-measured version:
// scalar VXf/er gathers with 1-ct lookahead, launch_bounds (256,3).
// ---------------------------------------------------------------------------
__global__ __launch_bounds__(256, 3) void k_edge_apply(
    const float* __restrict__ e,
    const unsigned short* __restrict__ W16,
    const float* __restrict__ Ue_b,
    const float* __restrict__ ws,
    float* __restrict__ out_e)
{
    __shared__ short Wl[16384];     // 32 KB bf16 W, swizzled
    int t   = threadIdx.x;
    int bx  = blockIdx.x;
    int bi  = bx >> 1, jh = bx & 1;
    int b   = bi >> 8;
    int wid = t >> 6, l = t & 63;
    int hsub = l & 15, g = l >> 4;
    int swz = (hsub & 7) << 4;
    int jbase = jh * 128 + wid * 32;

    const float* VXf  = ws + VX_OFF + (size_t)b * 32768;
    const float* eb   = e     + (size_t)bi * 32768;
    float*       oute = out_e + (size_t)bi * 32768;

    // pre-barrier issue: tile-0 raws + ct-0 operands + constants
    float4 raw[8];
    load_raw(eb, jbase + hsub, g, raw);
    float vx_pre[4], er_pre[4];
    #pragma unroll
    for (int r = 0; r < 4; ++r) {
        size_t idx = (size_t)(jbase + g * 4 + r) * 128 + hsub;
        vx_pre[r] = VXf[idx];
        er_pre[r] = eb[idx];
    }
    float biasv[8], sceR[8], sheR[8];
    #pragma unroll
    for (int ct = 0; ct < 8; ++ct) {
        int h = ct * 16 + hsub;
        biasv[ct] = Ue_b[h] + ws[VX_OFF + (size_t)bi * 128 + h];
        sceR[ct]  = ws[SCE_OFF + h];
        sheR[ct]  = ws[SHE_OFF + h];
    }

    const int4* Wg = (const int4*)W16;
    #pragma unroll
    for (int p = 0; p < 8; ++p) {
        int s = t + 256 * p;
        int r = s >> 4, c = s & 15;
        int addr = r * 256 + ((c * 16) ^ ((r & 7) << 4));
        *(int4*)((char*)Wl + addr) = Wg[s];
    }
    __syncthreads();

    bf16x8 afr[4];

    #pragma unroll
    for (int rt = 0; rt < 2; ++rt) {
        int jb = jbase + rt * 16;
        cvt_frag(raw, afr);
        if (rt == 0) load_raw(eb, jbase + 16 + hsub, g, raw);

        float vx_n[4], er_n[4];
        bf16x8 bfr_n[4];
        #pragma unroll
        for (int r = 0; r < 4; ++r) {
            if (rt == 0) { vx_n[r] = vx_pre[r]; er_n[r] = er_pre[r]; }
            else {
                size_t idx = (size_t)(jb + g * 4 + r) * 128 + hsub;
                vx_n[r] = VXf[idx];
                er_n[r] = eb[idx];
            }
        }
        #pragma unroll
        for (int kc = 0; kc < 4; ++kc) bfr_n[kc] = ldsW(Wl, hsub, kc, g, swz);

        #pragma unroll
        for (int ct = 0; ct < 8; ++ct) {
            float vx_c[4], er_c[4];
            bf16x8 bfr_c[4];
            #pragma unroll
            for (int r = 0; r < 4; ++r) { vx_c[r] = vx_n[r]; er_c[r] = er_n[r]; }
            #pragma unroll
            for (int kc = 0; kc < 4; ++kc) bfr_c[kc] = bfr_n[kc];

            if (ct < 7) {
                int hn = (ct + 1) * 16 + hsub;
                #pragma unroll
                for (int r = 0; r < 4; ++r) {
                    size_t idx = (size_t)(jb + g * 4 + r) * 128 + hn;
                    vx_n[r] = VXf[idx];
                    er_n[r] = eb[idx];
                }
                #pragma unroll
                for (int kc = 0; kc < 4; ++kc)
                    bfr_n[kc] = ldsW(Wl, hn, kc, g, swz);
            }

            f32x4 acc = {0.f, 0.f, 0.f, 0.f};
            #pragma unroll
            for (int kc = 0; kc < 4; ++kc)
                acc = __builtin_amdgcn_mfma_f32_16x16x32_bf16(afr[kc], bfr_c[kc], acc, 0, 0, 0);

            float bih = biasv[ct], sc = sceR[ct], sh = sheR[ct];
            int h = ct * 16 + hsub;
            #pragma unroll
            for (int r = 0; r < 4; ++r) {
                int j = jb + g * 4 + r;
                float v = acc[r] + bih + vx_c[r];
                float f = v * sc + sh;
                oute[(size_t)j * 128 + h] = er_c[r] + fmaxf(f, 0.0f);
            }
        }
    }
}

extern "C" void kernel_launch(void* const* d_in, const int* in_sizes, int n_in,
                              void* d_out, int out_size, void* d_ws, size_t ws_size,
                              hipStream_t stream)
{
    const float* x      = (const float*)d_in[0];
    const float* e      = (const float*)d_in[1];
    const float* Ue_w   = (const float*)d_in[2];
    const float* Ue_b   = (const float*)d_in[3];
    const float* Ve_w   = (const float*)d_in[4];
    const float* Ve_b   = (const float*)d_in[5];
    const float* Un_w   = (const float*)d_in[6];
    const float* Un_b   = (const float*)d_in[7];
    const float* Vn_w   = (const float*)d_in[8];
    const float* Vn_b   = (const float*)d_in[9];
    const float* bn_x_g = (const float*)d_in[10];
    const float* bn_x_b = (const float*)d_in[11];
    const float* bn_e_g = (const float*)d_in[12];
    const float* bn_e_b = (const float*)d_in[13];

    float* out   = (float*)d_out;
    float* out_x = out;                 // 131072 floats
    float* out_e = out + 131072;        // 33554432 floats
    float* ws    = (float*)d_ws;
    unsigned short* W16 = (unsigned short*)(ws + W16_OFF);

    k_prep       <<<64, 256, 0, stream>>>(Ue_w, W16);
    k_linx       <<<128, 256, 0, stream>>>(x, Ve_w, Ve_b, Vn_w, Vn_b, Un_w, Un_b, ws);
    k_edge_stats <<<2048, 256, 0, stream>>>(e, W16, Ue_b, ws);
    k_red        <<<64, 256, 0, stream>>>(ws);
    k_fin        <<<1, 128, 0, stream>>>(bn_x_g, bn_x_b, bn_e_g, bn_e_b, ws);
    k_xnew       <<<128, 256, 0, stream>>>(x, ws, out_x);
    k_edge_apply <<<2048, 256, 0, stream>>>(e, W16, Ue_b, ws, out_e);
}